// Round 1
// baseline (83.116 us; speedup 1.0000x reference)
//
#include <hip/hip_runtime.h>
#include <hip/hip_bf16.h>

// out[b,0,o0,o1,o2] = in[b, 1 + (n*14+g1)*14 + g2, ch]
//   i0 = o0*144/64 ; n = i0/9 ; c0 = i0%9
//   i1 = o1*126/64 ; g1 = i1/9; c1 = i1%9
//   i2 = o2*126/64 ; g2 = i2/9; c2 = i2%9
//   cc = (c0*9+c1)*9+c2 ; ch = floorf(cc * float32(768.0/729.0))  (match JAX f32 math)

#define TOKENS 3137
#define CHANNELS 768
#define OUTD 64

__global__ __launch_bounds__(256) void gather_kernel(const float* __restrict__ in,
                                                     float* __restrict__ out,
                                                     int total) {
    const float ch_scale = (float)(768.0 / 729.0);  // rounded to f32, same as JAX
    int gid = blockIdx.x * 256 + threadIdx.x;
    if (gid >= total) return;

    int o2  = gid & 63;
    int row = gid >> 6;
    int o1  = row & 63;
    int rr  = row >> 6;
    int o0  = rr & 63;
    int b   = rr >> 6;

    int i0 = (o0 * 144) >> 6;   // floor(o0 * 144/64), exact
    int i1 = (o1 * 126) >> 6;   // floor(o1 * 126/64), exact
    int i2 = (o2 * 126) >> 6;

    int n  = i0 / 9, c0 = i0 - n * 9;
    int g1 = i1 / 9, c1 = i1 - g1 * 9;
    int g2 = i2 / 9, c2 = i2 - g2 * 9;

    int cc = (c0 * 9 + c1) * 9 + c2;
    int ch = (int)floorf((float)cc * ch_scale);

    int t = 1 + (n * 14 + g1) * 14 + g2;

    long long src = ((long long)b * TOKENS + t) * CHANNELS + ch;
    out[gid] = in[src];
}

extern "C" void kernel_launch(void* const* d_in, const int* in_sizes, int n_in,
                              void* d_out, int out_size, void* d_ws, size_t ws_size,
                              hipStream_t stream) {
    const float* in = (const float*)d_in[0];
    float* out = (float*)d_out;
    int total = out_size;                 // 64 * 64 * 64 * 64 = 16,777,216
    int blocks = (total + 255) / 256;     // 65536
    gather_kernel<<<blocks, 256, 0, stream>>>(in, out, total);
}

// Round 2
// 82.005 us; speedup vs baseline: 1.0135x; 1.0135x over previous
//
#include <hip/hip_runtime.h>
#include <hip/hip_bf16.h>

// out[b,0,o0,o1,o2] = in[b, 1 + (n*14+g1)*14 + g2, ch]
//   i0 = floor(o0*144/64); n = i0/9; c0 = i0%9
//   i1 = floor(o1*126/64); g1 = i1/9; c1 = i1%9
//   i2 = floor(o2*126/64); g2 = i2/9; c2 = i2%9
//   cc = (c0*9+c1)*9+c2; ch = floorf(cc * float32(768.0/729.0))  (match JAX f32)
//
// MLP trick: o0 and o0+16 give i0 differing by exactly 36 -> same c0/ch,
// token index differs by 4*196=784. Each thread handles o0 = q + {0,16,32,48}
// with ONE index computation and 4 independent loads in flight.

#define TOKENS 3137
#define CHANNELS 768

__global__ __launch_bounds__(256) void gather4_kernel(const float* __restrict__ in,
                                                      float* __restrict__ out) {
    const float ch_scale = (float)(768.0 / 729.0);  // f32-rounded, same as JAX

    int gid = blockIdx.x * 256 + threadIdx.x;
    int o2 = gid & 63;
    int r  = gid >> 6;
    int o1 = r & 63;
    r >>= 6;
    int q  = r & 15;   // o0 base: o0 = q + 16*j, j=0..3
    int b  = r >> 4;

    int i0 = (q  * 144) >> 6;   // floor(9q/4), 0..33
    int i1 = (o1 * 126) >> 6;
    int i2 = (o2 * 126) >> 6;

    int nq = i0 / 9, c0 = i0 - nq * 9;
    int g1 = i1 / 9, c1 = i1 - g1 * 9;
    int g2 = i2 / 9, c2 = i2 - g2 * 9;

    int cc = (c0 * 9 + c1) * 9 + c2;
    int ch = (int)floorf((float)cc * ch_scale);

    int t = 1 + (nq * 14 + g1) * 14 + g2;

    const float* src = in + ((long long)(b * TOKENS + t) * CHANNELS + ch);
    // 4 independent loads (different tokens, same channel)
    float v0 = src[0];
    float v1 = src[1 * 784 * CHANNELS];
    float v2 = src[2 * 784 * CHANNELS];
    float v3 = src[3 * 784 * CHANNELS];

    float* dst = out + ((((b << 6) | q) << 6 | o1) << 6 | o2);
    dst[0 << 16] = v0;   // o0 = q
    dst[1 << 16] = v1;   // o0 = q+16
    dst[2 << 16] = v2;   // o0 = q+32
    dst[3 << 16] = v3;   // o0 = q+48
}

extern "C" void kernel_launch(void* const* d_in, const int* in_sizes, int n_in,
                              void* d_out, int out_size, void* d_ws, size_t ws_size,
                              hipStream_t stream) {
    const float* in = (const float*)d_in[0];
    float* out = (float*)d_out;
    // total threads = 64(b) * 16(q) * 64(o1) * 64(o2) = 4,194,304
    int blocks = 4194304 / 256;  // 16384
    gather4_kernel<<<blocks, 256, 0, stream>>>(in, out);
}